// Round 4
// baseline (9853.392 us; speedup 1.0000x reference)
//
#include <hip/hip_runtime.h>
#include <math.h>

#define NL 4
#define KC 1024
#define FD 512
#define MT 16
#define FC 8
#define TM 8
#define TN 8
#define BLK 256

// ---- numpy npyv(AVX512) pairwise-sum emulation over 128 squares ----------
// lane l16 partial: tree over m ((m0+m1)+(m2+m3))+((m4+m5)+(m6+m7)),
// element index m*16+l16. Products rounded fp32 first (numpy tmp=a*a).
__device__ __forceinline__ float np_chunk_partial(const float* p, int l16) {
  float pm[8];
#pragma unroll
  for (int m = 0; m < 8; m++) {
    float v = p[m * 16 + l16];
    pm[m] = __fmul_rn(v, v);
  }
  float a = __fadd_rn(__fadd_rn(pm[0], pm[1]), __fadd_rn(pm[2], pm[3]));
  float b = __fadd_rn(__fadd_rn(pm[4], pm[5]), __fadd_rn(pm[6], pm[7]));
  return __fadd_rn(a, b);
}

// ---- c2[l][k] = np.sum(cb*cb, axis=1) with numpy-pairwise fp32 order ----
__global__ __launch_bounds__(BLK) void c2_kernel(const float* __restrict__ cb,
                                                 float* __restrict__ c2) {
  int wid  = (blockIdx.x * BLK + threadIdx.x) >> 6;  // one wave per codeword
  int lane = threadIdx.x & 63;
  if (wid >= NL * KC) return;
  const float* row = cb + (size_t)wid * FD;
  int chunk = lane >> 4, l16 = lane & 15;
  float part = np_chunk_partial(row + chunk * 128, l16);
  // horizontal within 16-lane group: strides 8,4,2,1 (commutative-safe xor)
  part = __fadd_rn(part, __shfl_xor(part, 8));
  part = __fadd_rn(part, __shfl_xor(part, 4));
  part = __fadd_rn(part, __shfl_xor(part, 2));
  part = __fadd_rn(part, __shfl_xor(part, 1));
  // pairwise(512) = (b0+b1) + (b2+b3)
  float s1 = __fadd_rn(part, __shfl_xor(part, 16));
  float s  = __fadd_rn(s1, __shfl_xor(s1, 32));
  if (lane == 0) c2[wid] = s;
}

// ---- fused 4-layer RQ, bit-emulating the np fp32 reference ----------
__global__ __launch_bounds__(BLK, 2) void rq_kernel(
    const float* __restrict__ data, const float* __restrict__ cb,
    const float* __restrict__ c2g, float* __restrict__ codes_out,
    float* __restrict__ recon_out, int N) {
  __shared__ float resid[MT * FD];              // 32 KB fp32 residual (np chain)
  __shared__ __align__(16) float cbt[KC * FC];  // 32 KB codebook chunk / scratch
  __shared__ float sh_part[MT * 64];            // 4 KB x2 lane partials
  __shared__ float sh_x2[MT];
  __shared__ int hist_k[NL * MT];

  float* red_d = cbt;                     // [MT][128] scores
  int*   red_k = (int*)(cbt + MT * 128);  // [MT][128] indices

  const int t  = threadIdx.x;
  const int n0 = blockIdx.x * MT;
  if (n0 >= N) return;
  const int tm = t & 1;    // 2 point-groups of TM=8
  const int tk = t >> 1;   // 0..127 codeword-groups (k = tk + 128*j)

  // residual := data
#pragma unroll
  for (int q = 0; q < 8; q++) {
    int id = t + BLK * q;
    int m = id >> 7, c4 = id & 127;
    int mg = n0 + m; if (mg > N - 1) mg = N - 1;
    *(float4*)&resid[m * FD + c4 * 4] =
        *(const float4*)&data[(size_t)mg * FD + c4 * 4];
  }
  __syncthreads();

  for (int l = 0; l < NL; l++) {
    const float* cbl = cb + (size_t)l * KC * FD;

    // ---- x2[row] = np.sum(resid*resid, axis=1), numpy-pairwise order ----
    {
      int row = t >> 4, l16 = t & 15;
#pragma unroll
      for (int c = 0; c < 4; c++)
        sh_part[(row * 4 + c) * 16 + l16] =
            np_chunk_partial(&resid[row * FD + c * 128], l16);
    }
    __syncthreads();
    if (t < MT) {
      const float* P = &sh_part[t * 64];
      float b[4];
#pragma unroll
      for (int c = 0; c < 4; c++) {
        float u[8];
#pragma unroll
        for (int j2 = 0; j2 < 8; j2++)
          u[j2] = __fadd_rn(P[c * 16 + j2], P[c * 16 + j2 + 8]);
        float v[4];
#pragma unroll
        for (int j2 = 0; j2 < 4; j2++) v[j2] = __fadd_rn(u[j2], u[j2 + 4]);
        float w0 = __fadd_rn(v[0], v[2]);
        float w1 = __fadd_rn(v[1], v[3]);
        b[c] = __fadd_rn(w0, w1);
      }
      sh_x2[t] = __fadd_rn(__fadd_rn(b[0], b[1]), __fadd_rn(b[2], b[3]));
    }
    __syncthreads();

    // ---- GEMM: dot[row][k], sequential-k single-accumulator FMA chain ----
    float acc[TM][TN];
#pragma unroll
    for (int i = 0; i < TM; i++)
#pragma unroll
      for (int j = 0; j < TN; j++) acc[i][j] = 0.f;

    for (int fc = 0; fc < FD / FC; fc++) {
#pragma unroll
      for (int q = 0; q < 8; q++) {
        int id = t + BLK * q;          // 2048 float4s
        int k = id >> 1, h = id & 1;
        *(float4*)&cbt[id * 4] =
            *(const float4*)&cbl[(size_t)k * FD + fc * FC + h * 4];
      }
      __syncthreads();
#pragma unroll
      for (int s2 = 0; s2 < 2; s2++) {
        float4 rv[TM], cv[TN];
#pragma unroll
        for (int i = 0; i < TM; i++)
          rv[i] = *(const float4*)&resid[(tm * TM + i) * FD + fc * FC + s2 * 4];
#pragma unroll
        for (int j = 0; j < TN; j++)
          cv[j] = *(const float4*)&cbt[(tk + 128 * j) * FC + s2 * 4];
#pragma unroll
        for (int i = 0; i < TM; i++)
#pragma unroll
          for (int j = 0; j < TN; j++) {
            acc[i][j] = __fmaf_rn(rv[i].x, cv[j].x, acc[i][j]);
            acc[i][j] = __fmaf_rn(rv[i].y, cv[j].y, acc[i][j]);
            acc[i][j] = __fmaf_rn(rv[i].z, cv[j].z, acc[i][j]);
            acc[i][j] = __fmaf_rn(rv[i].w, cv[j].w, acc[i][j]);
          }
      }
      __syncthreads();
    }

    // ---- score s = fl(fl(x2 + c2[k]) - fl(2*dot)), ref fp32 semantics ----
    float c2v[TN];
#pragma unroll
    for (int j = 0; j < TN; j++) c2v[j] = c2g[l * KC + tk + 128 * j];
    float x2v[TM];
#pragma unroll
    for (int i = 0; i < TM; i++) x2v[i] = sh_x2[tm * TM + i];
#pragma unroll
    for (int i = 0; i < TM; i++) {
      float bd = INFINITY; int bk = 0x7fffffff;
#pragma unroll
      for (int j = 0; j < TN; j++) {   // k ascending: strict < = first-min
        float s = __fsub_rn(__fadd_rn(x2v[i], c2v[j]),
                            __fmul_rn(2.0f, acc[i][j]));
        int k = tk + 128 * j;
        if (s < bd) { bd = s; bk = k; }
      }
      int p = tm * TM + i;
      red_d[p * 128 + tk] = bd;
      red_k[p * 128 + tk] = bk;
    }
    __syncthreads();

    // block argmin, ties -> lowest k (np.argmin first occurrence)
    if (t < MT) {
      float bd = INFINITY; int bk = 0x7fffffff;
      for (int e = 0; e < 128; e++) {
        int idx = (e + 17 * t) & 127;   // bank-conflict-free rotation
        float d = red_d[t * 128 + idx];
        int   k = red_k[t * 128 + idx];
        if (d < bd || (d == bd && k < bk)) { bd = d; bk = k; }
      }
      hist_k[l * MT + t] = bk;
      if (n0 + t < N) codes_out[(size_t)(n0 + t) * NL + l] = (float)bk;
    }
    __syncthreads();

    if (l < NL - 1) {
      // residual -= chosen codeword (fp32 elementwise, np-exact)
#pragma unroll
      for (int q = 0; q < 8; q++) {
        int id = t + BLK * q;
        int m = id >> 7, c4 = id & 127;
        int bk2 = hist_k[l * MT + m];
        float4 qv = *(const float4*)&cbl[(size_t)bk2 * FD + c4 * 4];
        float4 rv = *(float4*)&resid[m * FD + c4 * 4];
        rv.x = __fsub_rn(rv.x, qv.x); rv.y = __fsub_rn(rv.y, qv.y);
        rv.z = __fsub_rn(rv.z, qv.z); rv.w = __fsub_rn(rv.w, qv.w);
        *(float4*)&resid[m * FD + c4 * 4] = rv;
      }
      __syncthreads();
    }
  }

  // ---- recon = ((q0+q1)+q2)+q3, np accumulation order ----
#pragma unroll
  for (int q = 0; q < 8; q++) {
    int id = t + BLK * q;
    int m = id >> 7, c4 = id & 127;
    int mg = n0 + m;
    if (mg < N) {
      float4 q0 = *(const float4*)&cb[((size_t)0 * KC + hist_k[0 * MT + m]) * FD + c4 * 4];
      float4 q1 = *(const float4*)&cb[((size_t)1 * KC + hist_k[1 * MT + m]) * FD + c4 * 4];
      float4 q2 = *(const float4*)&cb[((size_t)2 * KC + hist_k[2 * MT + m]) * FD + c4 * 4];
      float4 q3 = *(const float4*)&cb[((size_t)3 * KC + hist_k[3 * MT + m]) * FD + c4 * 4];
      float4 o;
      o.x = __fadd_rn(__fadd_rn(__fadd_rn(q0.x, q1.x), q2.x), q3.x);
      o.y = __fadd_rn(__fadd_rn(__fadd_rn(q0.y, q1.y), q2.y), q3.y);
      o.z = __fadd_rn(__fadd_rn(__fadd_rn(q0.z, q1.z), q2.z), q3.z);
      o.w = __fadd_rn(__fadd_rn(__fadd_rn(q0.w, q1.w), q2.w), q3.w);
      *(float4*)&recon_out[(size_t)mg * FD + c4 * 4] = o;
    }
  }
}

extern "C" void kernel_launch(void* const* d_in, const int* in_sizes, int n_in,
                              void* d_out, int out_size, void* d_ws, size_t ws_size,
                              hipStream_t stream) {
  const float* data = (const float*)d_in[0];     // [N,512] fp32
  const float* cb   = (const float*)d_in[1];     // [4,1024,512] fp32
  int N = in_sizes[0] / FD;

  float* c2        = (float*)d_ws;               // 4096 floats
  float* codes_out = (float*)d_out;              // [N,4] as float (int values)
  float* recon_out = codes_out + (size_t)N * NL; // [N,512]

  c2_kernel<<<(NL * KC + 3) / 4, BLK, 0, stream>>>(cb, c2);
  int nblocks = (N + MT - 1) / MT;
  rq_kernel<<<nblocks, BLK, 0, stream>>>(data, cb, c2, codes_out, recon_out, N);
}

// Round 5
// 3882.273 us; speedup vs baseline: 2.5380x; 2.5380x over previous
//
#include <hip/hip_runtime.h>
#include <hip/hip_bf16.h>
#include <math.h>

#define NL 4
#define KC 1024
#define FD 512
#define MT 16          // rows per block
#define BLK 256
#define RS 516         // resid LDS row stride (+4 floats: 2-way banks, 16B aligned)
#define NCAND 6

typedef __attribute__((ext_vector_type(8))) short short8;   // 8 bf16 (4 VGPRs)
typedef __attribute__((ext_vector_type(4))) float f32x4;    // MFMA acc

__device__ __forceinline__ short bf16c(float x) {
  __hip_bfloat16 h = __float2bfloat16(x);
  return *reinterpret_cast<short*>(&h);
}

// ---- numpy pairwise-sum emulation over 128 squares (verified bit-exact R4) --
__device__ __forceinline__ float np_chunk_partial(const float* p, int l16) {
  float pm[8];
#pragma unroll
  for (int m = 0; m < 8; m++) {
    float v = p[m * 16 + l16];
    pm[m] = __fmul_rn(v, v);
  }
  float a = __fadd_rn(__fadd_rn(pm[0], pm[1]), __fadd_rn(pm[2], pm[3]));
  float b = __fadd_rn(__fadd_rn(pm[4], pm[5]), __fadd_rn(pm[6], pm[7]));
  return __fadd_rn(a, b);
}

// ---- c2[l][k] = np.sum(cb*cb, axis=1), np-pairwise fp32 (verified R4) ------
__global__ __launch_bounds__(BLK) void c2_kernel(const float* __restrict__ cb,
                                                 float* __restrict__ c2) {
  int wid  = (blockIdx.x * BLK + threadIdx.x) >> 6;
  int lane = threadIdx.x & 63;
  if (wid >= NL * KC) return;
  const float* row = cb + (size_t)wid * FD;
  int chunk = lane >> 4, l16 = lane & 15;
  float part = np_chunk_partial(row + chunk * 128, l16);
  part = __fadd_rn(part, __shfl_xor(part, 8));
  part = __fadd_rn(part, __shfl_xor(part, 4));
  part = __fadd_rn(part, __shfl_xor(part, 2));
  part = __fadd_rn(part, __shfl_xor(part, 1));
  float s1 = __fadd_rn(part, __shfl_xor(part, 16));
  float s  = __fadd_rn(s1, __shfl_xor(s1, 32));
  if (lane == 0) c2[wid] = s;
}

// ---- swizzle cb fp32 -> bf16 in B-fragment order ----------------------------
// frag w = ((l*16 + c)*64 + T): element [lane][j] = cb[l][T*16+(lane&15)]
//                                                    [c*32+(lane>>4)*8+j]
// so a wave's b-frag load for (l,c,T) is one fully-coalesced 1KB dwordx4.
__global__ __launch_bounds__(BLK) void swz_kernel(const float* __restrict__ cb,
                                                  short* __restrict__ cbw) {
  int g = blockIdx.x * BLK + threadIdx.x;
  int w = g >> 6, lane = g & 63;
  if (w >= NL * 16 * 64) return;
  int l = w >> 10, c = (w >> 6) & 15, T = w & 63;
  int kidx = T * 16 + (lane & 15);
  int f0   = c * 32 + ((lane >> 4) << 3);
  const float* src = cb + (((size_t)l * KC + kidx) * FD + f0);
  short8 v;
#pragma unroll
  for (int j = 0; j < 8; j++) v[j] = bf16c(src[j]);
  *(short8*)(cbw + (size_t)w * 512 + lane * 8) = v;
}

// ---- fused 4-layer RQ: bf16-MFMA filter -> top-6 -> bit-exact fp32 rescore --
__global__ __launch_bounds__(BLK, 2) void rq_kernel(
    const float* __restrict__ data, const float* __restrict__ cb,
    const float* __restrict__ c2g, const short* __restrict__ cbw,
    float* __restrict__ codes_out, float* __restrict__ recon_out, int N) {
  __shared__ float resid[MT * RS];        // 33 KB exact fp32 residual
  __shared__ float pool_d[MT * 128];      // 8 KB filter pool scores
  __shared__ int   pool_k[MT * 128];      // 8 KB filter pool indices
  __shared__ float mrg_d[MT * 24];
  __shared__ int   mrg_k[MT * 24];
  __shared__ float sh_part[MT * 64];      // x2 lane partials
  __shared__ float sh_x2[MT];
  __shared__ float sc_d[MT * NCAND];
  __shared__ int   sc_k[MT * NCAND];
  __shared__ int   cand_k[MT * NCAND];
  __shared__ int   hist_k[NL * MT];

  const int t    = threadIdx.x;
  const int n0   = blockIdx.x * MT;
  if (n0 >= N) return;
  const int wv   = t >> 6;
  const int lane = t & 63;
  const int l15  = lane & 15;
  const int lq   = lane >> 4;

  // residual := data (rows clamped; clamped rows never write outputs)
#pragma unroll
  for (int q = 0; q < 8; q++) {
    int id = t + BLK * q;
    int m = id >> 7, c4 = id & 127;
    int mg = n0 + m; if (mg > N - 1) mg = N - 1;
    *(float4*)&resid[m * RS + c4 * 4] =
        *(const float4*)&data[(size_t)mg * FD + c4 * 4];
  }
  __syncthreads();

  for (int l = 0; l < NL; l++) {
    const float* cbl = cb + (size_t)l * KC * FD;

    // ---- exact x2[row], np-pairwise (verified R4) ----
    {
      int row = t >> 4, j16 = t & 15;
#pragma unroll
      for (int c = 0; c < 4; c++)
        sh_part[(row * 4 + c) * 16 + j16] =
            np_chunk_partial(&resid[row * RS + c * 128], j16);
    }
    __syncthreads();
    if (t < MT) {
      const float* P = &sh_part[t * 64];
      float b[4];
#pragma unroll
      for (int c = 0; c < 4; c++) {
        float u[8];
#pragma unroll
        for (int j2 = 0; j2 < 8; j2++)
          u[j2] = __fadd_rn(P[c * 16 + j2], P[c * 16 + j2 + 8]);
        float v[4];
#pragma unroll
        for (int j2 = 0; j2 < 4; j2++) v[j2] = __fadd_rn(u[j2], u[j2 + 4]);
        b[c] = __fadd_rn(__fadd_rn(v[0], v[2]), __fadd_rn(v[1], v[3]));
      }
      sh_x2[t] = __fadd_rn(__fadd_rn(b[0], b[1]), __fadd_rn(b[2], b[3]));
    }
    __syncthreads();

    // ---- bf16 MFMA filter GEMM: wave wv covers cols wv*256..+255 ----
    f32x4 acc[16];
#pragma unroll
    for (int tt = 0; tt < 16; tt++) acc[tt] = (f32x4)0.f;

    float c2f[16];
#pragma unroll
    for (int tt = 0; tt < 16; tt++)
      c2f[tt] = c2g[l * KC + wv * 256 + tt * 16 + l15];

    for (int ch = 0; ch < 16; ch++) {
      // A-frag: A[m=lane&15][k=(lane>>4)*8+j] from exact residual, cvt bf16
      float4 alo = *(const float4*)&resid[l15 * RS + ch * 32 + lq * 8];
      float4 ahi = *(const float4*)&resid[l15 * RS + ch * 32 + lq * 8 + 4];
      short8 av;
      av[0] = bf16c(alo.x); av[1] = bf16c(alo.y);
      av[2] = bf16c(alo.z); av[3] = bf16c(alo.w);
      av[4] = bf16c(ahi.x); av[5] = bf16c(ahi.y);
      av[6] = bf16c(ahi.z); av[7] = bf16c(ahi.w);
      const short8* bp =
          (const short8*)(cbw + (((size_t)l * 16 + ch) * 64 + wv * 16) * 512);
#pragma unroll
      for (int tt = 0; tt < 16; tt++) {
        short8 bv = bp[tt * 64 + lane];   // coalesced 1KB per wave
        acc[tt] = __builtin_amdgcn_mfma_f32_16x16x32_bf16(av, bv, acc[tt],
                                                          0, 0, 0);
      }
    }

    // ---- filter scores -> per-lane top-2 -> pool[row][128] ----
    // C layout (m89): col=lane&15, row=(lane>>4)*4+reg
#pragma unroll
    for (int g = 0; g < 4; g++) {
      float b1 = INFINITY, b2 = INFINITY; int k1 = 0x7fffffff, k2 = 0x7fffffff;
#pragma unroll
      for (int tt = 0; tt < 16; tt++) {
        float s = c2f[tt] - 2.0f * acc[tt][g];
        int k = wv * 256 + tt * 16 + l15;
        if (s < b1) { b2 = b1; k2 = k1; b1 = s; k1 = k; }
        else if (s < b2) { b2 = s; k2 = k; }
      }
      int r = lq * 4 + g;
      int base = r * 128 + wv * 32 + l15 * 2;
      pool_d[base] = b1; pool_k[base] = k1;
      pool_d[base + 1] = b2; pool_k[base + 1] = k2;
    }
    __syncthreads();

    // ---- stage A: 4 scanners/row, top-6 over 32 entries each ----
    if (t < 64) {
      int r = t >> 2, seg = t & 3;
      float cd[NCAND]; int ck[NCAND];
#pragma unroll
      for (int j = 0; j < NCAND; j++) { cd[j] = INFINITY; ck[j] = 0x7fffffff; }
      for (int e = 0; e < 32; e++) {
        int idx = seg * 32 + ((e + t) & 31);   // rotate: conflict-free
        float d = pool_d[r * 128 + idx];
        int   k = pool_k[r * 128 + idx];
#pragma unroll
        for (int j = 0; j < NCAND; j++) {
          bool better = (d < cd[j]) || (d == cd[j] && k < ck[j]);
          if (better) { float td = cd[j]; cd[j] = d; d = td;
                        int   tk = ck[j]; ck[j] = k; k = tk; }
        }
      }
#pragma unroll
      for (int j = 0; j < NCAND; j++) {
        mrg_d[r * 24 + seg * NCAND + j] = cd[j];
        mrg_k[r * 24 + seg * NCAND + j] = ck[j];
      }
    }
    __syncthreads();

    // ---- stage B: merge 24 -> top-6 candidates ----
    if (t < MT) {
      float cd[NCAND]; int ck[NCAND];
#pragma unroll
      for (int j = 0; j < NCAND; j++) { cd[j] = INFINITY; ck[j] = 0x7fffffff; }
      for (int e = 0; e < 24; e++) {
        float d = mrg_d[t * 24 + e];
        int   k = mrg_k[t * 24 + e];
#pragma unroll
        for (int j = 0; j < NCAND; j++) {
          bool better = (d < cd[j]) || (d == cd[j] && k < ck[j]);
          if (better) { float td = cd[j]; cd[j] = d; d = td;
                        int   tk = ck[j]; ck[j] = k; k = tk; }
        }
      }
#pragma unroll
      for (int j = 0; j < NCAND; j++) cand_k[t * NCAND + j] = ck[j];
    }
    __syncthreads();

    // ---- bit-exact fp32 rescore of candidates (verified recipe from R4):
    // s = fl(fl(x2 + c2[k]) - fl(2*dot)), dot = sequential-f single FMA chain
    if (t < MT * NCAND) {
      int r = t / NCAND, c = t - r * NCAND;
      int k = cand_k[r * NCAND + c];
      const float* cw = cbl + (size_t)k * FD;
      float sum = 0.f;
#pragma unroll 8
      for (int i = 0; i < 128; i++) {
        float4 rv = *(const float4*)&resid[r * RS + i * 4];
        float4 qv = *(const float4*)&cw[i * 4];
        sum = __fmaf_rn(rv.x, qv.x, sum);
        sum = __fmaf_rn(rv.y, qv.y, sum);
        sum = __fmaf_rn(rv.z, qv.z, sum);
        sum = __fmaf_rn(rv.w, qv.w, sum);
      }
      float c2e = c2g[l * KC + k];
      sc_d[r * NCAND + c] = __fsub_rn(__fadd_rn(sh_x2[r], c2e),
                                      __fmul_rn(2.0f, sum));
      sc_k[r * NCAND + c] = k;
    }
    __syncthreads();

    // ---- exact argmin among candidates, ties -> lowest k ----
    if (t < MT) {
      float bd = INFINITY; int bk = 0x7fffffff;
#pragma unroll
      for (int c = 0; c < NCAND; c++) {
        float d = sc_d[t * NCAND + c];
        int   k = sc_k[t * NCAND + c];
        if (d < bd || (d == bd && k < bk)) { bd = d; bk = k; }
      }
      hist_k[l * MT + t] = bk;
      if (n0 + t < N) codes_out[(size_t)(n0 + t) * NL + l] = (float)bk;
    }
    __syncthreads();

    if (l < NL - 1) {
      // exact fp32 residual update (np elementwise)
#pragma unroll
      for (int q = 0; q < 8; q++) {
        int id = t + BLK * q;
        int m = id >> 7, c4 = id & 127;
        int bk2 = hist_k[l * MT + m];
        float4 qv = *(const float4*)&cbl[(size_t)bk2 * FD + c4 * 4];
        float4 rv = *(float4*)&resid[m * RS + c4 * 4];
        rv.x = __fsub_rn(rv.x, qv.x); rv.y = __fsub_rn(rv.y, qv.y);
        rv.z = __fsub_rn(rv.z, qv.z); rv.w = __fsub_rn(rv.w, qv.w);
        *(float4*)&resid[m * RS + c4 * 4] = rv;
      }
      __syncthreads();
    }
  }

  // ---- recon = ((q0+q1)+q2)+q3, np order (verified R4) ----
#pragma unroll
  for (int q = 0; q < 8; q++) {
    int id = t + BLK * q;
    int m = id >> 7, c4 = id & 127;
    int mg = n0 + m;
    if (mg < N) {
      float4 q0 = *(const float4*)&cb[((size_t)0 * KC + hist_k[0 * MT + m]) * FD + c4 * 4];
      float4 q1 = *(const float4*)&cb[((size_t)1 * KC + hist_k[1 * MT + m]) * FD + c4 * 4];
      float4 q2 = *(const float4*)&cb[((size_t)2 * KC + hist_k[2 * MT + m]) * FD + c4 * 4];
      float4 q3 = *(const float4*)&cb[((size_t)3 * KC + hist_k[3 * MT + m]) * FD + c4 * 4];
      float4 o;
      o.x = __fadd_rn(__fadd_rn(__fadd_rn(q0.x, q1.x), q2.x), q3.x);
      o.y = __fadd_rn(__fadd_rn(__fadd_rn(q0.y, q1.y), q2.y), q3.y);
      o.z = __fadd_rn(__fadd_rn(__fadd_rn(q0.z, q1.z), q2.z), q3.z);
      o.w = __fadd_rn(__fadd_rn(__fadd_rn(q0.w, q1.w), q2.w), q3.w);
      *(float4*)&recon_out[(size_t)mg * FD + c4 * 4] = o;
    }
  }
}

extern "C" void kernel_launch(void* const* d_in, const int* in_sizes, int n_in,
                              void* d_out, int out_size, void* d_ws, size_t ws_size,
                              hipStream_t stream) {
  const float* data = (const float*)d_in[0];     // [N,512] fp32
  const float* cb   = (const float*)d_in[1];     // [4,1024,512] fp32
  int N = in_sizes[0] / FD;

  float* c2  = (float*)d_ws;                         // 16 KB
  short* cbw = (short*)((char*)d_ws + 16384);        // 4 MB bf16 swizzled
  float* codes_out = (float*)d_out;
  float* recon_out = codes_out + (size_t)N * NL;

  c2_kernel<<<(NL * KC + 3) / 4, BLK, 0, stream>>>(cb, c2);
  swz_kernel<<<(NL * 16 * 64) / 4, BLK, 0, stream>>>(cb, cbw);
  int nblocks = (N + MT - 1) / MT;
  rq_kernel<<<nblocks, BLK, 0, stream>>>(data, cb, c2, cbw, codes_out,
                                         recon_out, N);
}